// Round 1
// baseline (3702.188 us; speedup 1.0000x reference)
//
#include <hip/hip_runtime.h>

// LightGCN forward: 3-layer propagation on a 150k-node graph, D=64.
// Structure: init (ego -> cur, acc) ; 3x { zero next; scatter-atomic spmm;
// acc += next; swap } ; scale acc by 1/4 in place (acc lives in d_out's
// final-embedding region) ; gather the 3x4096 selected rows.

#define U_CNT 100000
#define I_CNT 50000
#define N_CNT 150000
#define DIM 64
#define NNZ_CNT 6000000
#define NSEL 4096

__global__ void init_kernel(const float* __restrict__ user_emb,
                            const float* __restrict__ item_emb,
                            float* __restrict__ cur,
                            float* __restrict__ acc) {
    const int total = N_CNT * DIM / 4;       // float4 count
    const int ubound = U_CNT * DIM / 4;
    const float4* ue = (const float4*)user_emb;
    const float4* ie = (const float4*)item_emb;
    float4* c4 = (float4*)cur;
    float4* a4 = (float4*)acc;
    for (int i = blockIdx.x * blockDim.x + threadIdx.x; i < total;
         i += gridDim.x * blockDim.x) {
        float4 v = (i < ubound) ? ue[i] : ie[i - ubound];
        c4[i] = v;
        a4[i] = v;
    }
}

// Wave-per-64-edges scatter SpMM: y[row] += val * x[col]  (y pre-zeroed).
// lane == dim (D == wavefront size == 64). Each lane loads one edge's
// metadata coalesced, then the wave iterates the 64 edges via shuffle
// broadcast; gather + atomic are fully coalesced 256B row accesses.
__global__ void spmm_kernel(const float* __restrict__ val,
                            const int* __restrict__ row,
                            const int* __restrict__ col,
                            const float* __restrict__ x,
                            float* __restrict__ y) {
    const int lane = threadIdx.x & 63;
    const int waveInBlock = threadIdx.x >> 6;
    const int wavesPerBlock = blockDim.x >> 6;
    const int gw = blockIdx.x * wavesPerBlock + waveInBlock;
    const int totalWaves = gridDim.x * wavesPerBlock;
    for (int base = gw * 64; base < NNZ_CNT; base += totalWaves * 64) {
        // NNZ_CNT % 64 == 0, so a full group of 64 edges is always valid.
        const int e = base + lane;
        const float v = val[e];
        const int r = row[e];
        const int c = col[e];
        #pragma unroll 8
        for (int k = 0; k < 64; ++k) {
            const float vk = __shfl(v, k);
            const int rk = __shfl(r, k);
            const int ck = __shfl(c, k);
            const float xv = x[ck * DIM + lane];
            atomicAdd(&y[rk * DIM + lane], vk * xv);
        }
    }
}

__global__ void accum_kernel(float* __restrict__ acc,
                             const float* __restrict__ nxt) {
    const int total = N_CNT * DIM / 4;
    float4* a4 = (float4*)acc;
    const float4* n4 = (const float4*)nxt;
    for (int i = blockIdx.x * blockDim.x + threadIdx.x; i < total;
         i += gridDim.x * blockDim.x) {
        float4 a = a4[i];
        const float4 n = n4[i];
        a.x += n.x; a.y += n.y; a.z += n.z; a.w += n.w;
        a4[i] = a;
    }
}

__global__ void scale_kernel(float* __restrict__ acc) {
    const int total = N_CNT * DIM / 4;
    float4* a4 = (float4*)acc;
    for (int i = blockIdx.x * blockDim.x + threadIdx.x; i < total;
         i += gridDim.x * blockDim.x) {
        float4 a = a4[i];
        a.x *= 0.25f; a.y *= 0.25f; a.z *= 0.25f; a.w *= 0.25f;
        a4[i] = a;
    }
}

// out rows: [users | pos_items(+U) | neg_items(+U)] gathered from final.
__global__ void gather_kernel(const float* __restrict__ final_emb,
                              const int* __restrict__ users,
                              const int* __restrict__ pos,
                              const int* __restrict__ neg,
                              float* __restrict__ out) {
    const int total = 3 * NSEL * (DIM / 4);  // float4 granularity
    const float4* f4 = (const float4*)final_emb;
    float4* o4 = (float4*)out;
    for (int i = blockIdx.x * blockDim.x + threadIdx.x; i < total;
         i += gridDim.x * blockDim.x) {
        const int rowi = i / (DIM / 4);
        const int d4 = i % (DIM / 4);
        int src;
        if (rowi < NSEL) {
            src = users[rowi];
        } else if (rowi < 2 * NSEL) {
            src = U_CNT + pos[rowi - NSEL];
        } else {
            src = U_CNT + neg[rowi - 2 * NSEL];
        }
        o4[i] = f4[src * (DIM / 4) + d4];
    }
}

extern "C" void kernel_launch(void* const* d_in, const int* in_sizes, int n_in,
                              void* d_out, int out_size, void* d_ws, size_t ws_size,
                              hipStream_t stream) {
    const float* user_emb  = (const float*)d_in[0];
    const float* item_emb  = (const float*)d_in[1];
    const float* adj_val   = (const float*)d_in[2];
    const int*   adj_row   = (const int*)d_in[3];
    const int*   adj_col   = (const int*)d_in[4];
    const int*   users     = (const int*)d_in[5];
    const int*   pos_items = (const int*)d_in[6];
    const int*   neg_items = (const int*)d_in[7];
    // d_in[8] = num_layers (device scalar). Fixed at 3 by the problem; reading
    // it would need a host sync which is graph-capture-illegal. Hardcoded.

    float* out       = (float*)d_out;
    float* out_sel   = out;                        // 3*4096*64
    float* final_emb = out + (size_t)3 * NSEL * DIM; // N*64 (u_g then i_g)
    float* acc       = final_emb;                  // accumulate in place

    float* bufA = (float*)d_ws;
    float* bufB = bufA + (size_t)N_CNT * DIM;

    init_kernel<<<2048, 256, 0, stream>>>(user_emb, item_emb, bufA, acc);

    float* cur = bufA;
    float* nxt = bufB;
    for (int l = 0; l < 3; ++l) {
        hipMemsetAsync(nxt, 0, (size_t)N_CNT * DIM * sizeof(float), stream);
        spmm_kernel<<<2048, 256, 0, stream>>>(adj_val, adj_row, adj_col, cur, nxt);
        accum_kernel<<<2048, 256, 0, stream>>>(acc, nxt);
        float* t = cur; cur = nxt; nxt = t;
    }

    scale_kernel<<<2048, 256, 0, stream>>>(acc);
    gather_kernel<<<768, 256, 0, stream>>>(final_emb, users, pos_items, neg_items,
                                           out_sel);
}

// Round 2
// 1248.031 us; speedup vs baseline: 2.9664x; 2.9664x over previous
//
#include <hip/hip_runtime.h>

// LightGCN forward, D=64, N=150k, NNZ=6M, 3 layers.
// Strategy: build CSR once per call (histogram -> 3-kernel exclusive scan ->
// scatter into packed (col,val) int2 pairs), then gather-based SpMM with one
// wave per row (lane == dim), no float atomics. acc accumulation and the /4
// scale are fused into init/spmm. Falls back to the round-1 scatter-atomic
// path if ws_size is too small for the CSR buffers.

#define U_CNT 100000
#define I_CNT 50000
#define N_CNT 150000
#define DIM 64
#define NNZ_CNT 6000000
#define NSEL 4096

#define SCAN_BLK 256
#define SCAN_NBLK ((N_CNT + SCAN_BLK - 1) / SCAN_BLK)   // 586

// ---------------- shared small kernels ----------------

// init: cur = ego ; acc = 0.25 * ego   (acc pre-scaled so no final scale pass)
__global__ void init_kernel(const float* __restrict__ user_emb,
                            const float* __restrict__ item_emb,
                            float* __restrict__ cur,
                            float* __restrict__ acc) {
    const int total = N_CNT * DIM / 4;
    const int ubound = U_CNT * DIM / 4;
    const float4* ue = (const float4*)user_emb;
    const float4* ie = (const float4*)item_emb;
    float4* c4 = (float4*)cur;
    float4* a4 = (float4*)acc;
    for (int i = blockIdx.x * blockDim.x + threadIdx.x; i < total;
         i += gridDim.x * blockDim.x) {
        float4 v = (i < ubound) ? ue[i] : ie[i - ubound];
        c4[i] = v;
        float4 a = v;
        a.x *= 0.25f; a.y *= 0.25f; a.z *= 0.25f; a.w *= 0.25f;
        a4[i] = a;
    }
}

// out rows: [users | pos_items(+U) | neg_items(+U)] gathered from final.
__global__ void gather_kernel(const float* __restrict__ final_emb,
                              const int* __restrict__ users,
                              const int* __restrict__ pos,
                              const int* __restrict__ neg,
                              float* __restrict__ out) {
    const int total = 3 * NSEL * (DIM / 4);
    const float4* f4 = (const float4*)final_emb;
    float4* o4 = (float4*)out;
    for (int i = blockIdx.x * blockDim.x + threadIdx.x; i < total;
         i += gridDim.x * blockDim.x) {
        const int rowi = i / (DIM / 4);
        const int d4 = i % (DIM / 4);
        int src;
        if (rowi < NSEL) {
            src = users[rowi];
        } else if (rowi < 2 * NSEL) {
            src = U_CNT + pos[rowi - NSEL];
        } else {
            src = U_CNT + neg[rowi - 2 * NSEL];
        }
        o4[i] = f4[src * (DIM / 4) + d4];
    }
}

// ---------------- CSR build ----------------

__global__ void hist_kernel(const int* __restrict__ row, int* __restrict__ cnt) {
    for (int e = blockIdx.x * blockDim.x + threadIdx.x; e < NNZ_CNT;
         e += gridDim.x * blockDim.x) {
        atomicAdd(&cnt[row[e]], 1);
    }
}

// scanA: per-block inclusive scan of cnt -> off holds within-block EXCLUSIVE
// prefix; partials[blockIdx] = block total.
__global__ void scanA_kernel(const int* __restrict__ cnt,
                             int* __restrict__ off,
                             int* __restrict__ partials) {
    __shared__ int sdata[SCAN_BLK];
    const int tid = threadIdx.x;
    const int i = blockIdx.x * SCAN_BLK + tid;
    const int v = (i < N_CNT) ? cnt[i] : 0;
    sdata[tid] = v;
    __syncthreads();
    for (int d = 1; d < SCAN_BLK; d <<= 1) {
        int t = (tid >= d) ? sdata[tid - d] : 0;
        __syncthreads();
        sdata[tid] += t;
        __syncthreads();
    }
    if (i < N_CNT) off[i] = sdata[tid] - v;          // exclusive within block
    if (tid == SCAN_BLK - 1) partials[blockIdx.x] = sdata[tid];
}

// scanB: single block exclusive scan of the 586 block totals.
__global__ void scanB_kernel(int* __restrict__ partials) {
    __shared__ int sdata[1024];
    const int tid = threadIdx.x;
    const int v = (tid < SCAN_NBLK) ? partials[tid] : 0;
    sdata[tid] = v;
    __syncthreads();
    for (int d = 1; d < 1024; d <<= 1) {
        int t = (tid >= d) ? sdata[tid - d] : 0;
        __syncthreads();
        sdata[tid] += t;
        __syncthreads();
    }
    if (tid < SCAN_NBLK) partials[tid] = sdata[tid] - v;  // exclusive
}

// scanC: add block offset; also init cursor copy; write sentinel off[N]=NNZ.
__global__ void scanC_kernel(int* __restrict__ off,
                             const int* __restrict__ partials,
                             int* __restrict__ cursor) {
    const int i = blockIdx.x * SCAN_BLK + threadIdx.x;
    if (i < N_CNT) {
        const int o = off[i] + partials[blockIdx.x];
        off[i] = o;
        cursor[i] = o;
    }
    if (i == 0) off[N_CNT] = NNZ_CNT;
}

// scatter edges into row-sorted order as packed (col, val-bits).
__global__ void scatter_kernel(const float* __restrict__ val,
                               const int* __restrict__ row,
                               const int* __restrict__ col,
                               int* __restrict__ cursor,
                               int2* __restrict__ edges) {
    for (int e = blockIdx.x * blockDim.x + threadIdx.x; e < NNZ_CNT;
         e += gridDim.x * blockDim.x) {
        const int r = row[e];
        const int p = atomicAdd(&cursor[r], 1);
        edges[p] = make_int2(col[e], __float_as_int(val[e]));
    }
}

// ---------------- gather SpMM ----------------
// One wave per row; lane == dim. y[r] = sum val*x[col]; acc[r] += 0.25*y[r].
__global__ void spmm_csr_kernel(const int2* __restrict__ edges,
                                const int* __restrict__ off,
                                const float* __restrict__ x,
                                float* __restrict__ y,
                                float* __restrict__ acc,
                                int write_y) {
    const int lane = threadIdx.x & 63;
    const int gw = (blockIdx.x * blockDim.x + threadIdx.x) >> 6;
    const int totalWaves = (gridDim.x * blockDim.x) >> 6;
    for (int r = gw; r < N_CNT; r += totalWaves) {
        const int beg = off[r];
        const int end = off[r + 1];
        float s = 0.f;
        #pragma unroll 4
        for (int e = beg; e < end; ++e) {
            const int2 ev = edges[e];                    // wave-uniform 8B
            s += __int_as_float(ev.y) * x[(size_t)ev.x * DIM + lane];
        }
        const size_t oi = (size_t)r * DIM + lane;
        if (write_y) y[oi] = s;
        acc[oi] += 0.25f * s;
    }
}

// ---------------- fallback (round-1) scatter-atomic SpMM ----------------

__global__ void spmm_atomic_kernel(const float* __restrict__ val,
                                   const int* __restrict__ row,
                                   const int* __restrict__ col,
                                   const float* __restrict__ x,
                                   float* __restrict__ y) {
    const int lane = threadIdx.x & 63;
    const int gw = (blockIdx.x * blockDim.x + threadIdx.x) >> 6;
    const int totalWaves = (gridDim.x * blockDim.x) >> 6;
    for (int base = gw * 64; base < NNZ_CNT; base += totalWaves * 64) {
        const int e = base + lane;
        const float v = val[e];
        const int r = row[e];
        const int c = col[e];
        #pragma unroll 8
        for (int k = 0; k < 64; ++k) {
            const float vk = __shfl(v, k);
            const int rk = __shfl(r, k);
            const int ck = __shfl(c, k);
            atomicAdd(&y[rk * DIM + lane], vk * x[ck * DIM + lane]);
        }
    }
}

__global__ void accum_scale_kernel(float* __restrict__ acc,
                                   const float* __restrict__ nxt,
                                   float wacc) {
    const int total = N_CNT * DIM / 4;
    float4* a4 = (float4*)acc;
    const float4* n4 = (const float4*)nxt;
    for (int i = blockIdx.x * blockDim.x + threadIdx.x; i < total;
         i += gridDim.x * blockDim.x) {
        float4 a = a4[i];
        const float4 n = n4[i];
        a.x += wacc * n.x; a.y += wacc * n.y; a.z += wacc * n.z; a.w += wacc * n.w;
        a4[i] = a;
    }
}

// ---------------- launch ----------------

extern "C" void kernel_launch(void* const* d_in, const int* in_sizes, int n_in,
                              void* d_out, int out_size, void* d_ws, size_t ws_size,
                              hipStream_t stream) {
    const float* user_emb  = (const float*)d_in[0];
    const float* item_emb  = (const float*)d_in[1];
    const float* adj_val   = (const float*)d_in[2];
    const int*   adj_row   = (const int*)d_in[3];
    const int*   adj_col   = (const int*)d_in[4];
    const int*   users     = (const int*)d_in[5];
    const int*   pos_items = (const int*)d_in[6];
    const int*   neg_items = (const int*)d_in[7];
    // d_in[8] = num_layers, fixed at 3 (device scalar; host read would break
    // graph capture).

    float* out       = (float*)d_out;
    float* out_sel   = out;
    float* final_emb = out + (size_t)3 * NSEL * DIM;   // u_g then i_g, N x 64
    float* acc       = final_emb;

    const size_t NB = (size_t)N_CNT * DIM * sizeof(float);   // 38,400,000
    char* ws = (char*)d_ws;
    float* bufA = (float*)(ws + 0);
    float* bufB = (float*)(ws + NB);

    // CSR region layout (all 16B-aligned)
    const size_t offE   = 2 * NB;                        // edges: 48,000,000
    const size_t offOff = offE + (size_t)NNZ_CNT * 8;    // off: 600,016
    const size_t offCur = offOff + 600016;               // cursor: 600,000
    const size_t offCnt = offCur + 600000;               // cnt: 600,000
    const size_t offP   = offCnt + 600000;               // partials: 4,096
    const size_t needed = offP + 4096;

    init_kernel<<<2048, 256, 0, stream>>>(user_emb, item_emb, bufA, acc);

    if (ws_size >= needed) {
        int2* edges   = (int2*)(ws + offE);
        int*  offp    = (int*)(ws + offOff);
        int*  cursor  = (int*)(ws + offCur);
        int*  cnt     = (int*)(ws + offCnt);
        int*  partial = (int*)(ws + offP);

        hipMemsetAsync(cnt, 0, N_CNT * sizeof(int), stream);
        hist_kernel<<<2048, 256, 0, stream>>>(adj_row, cnt);
        scanA_kernel<<<SCAN_NBLK, SCAN_BLK, 0, stream>>>(cnt, offp, partial);
        scanB_kernel<<<1, 1024, 0, stream>>>(partial);
        scanC_kernel<<<SCAN_NBLK, SCAN_BLK, 0, stream>>>(offp, partial, cursor);
        scatter_kernel<<<2048, 256, 0, stream>>>(adj_val, adj_row, adj_col,
                                                 cursor, edges);

        float* cur = bufA;
        float* nxt = bufB;
        for (int l = 0; l < 3; ++l) {
            spmm_csr_kernel<<<2048, 256, 0, stream>>>(edges, offp, cur, nxt, acc,
                                                      (l < 2) ? 1 : 0);
            float* t = cur; cur = nxt; nxt = t;
        }
    } else {
        // fallback: round-1 scatter-atomic path (acc pre-scaled => wacc=0.25)
        float* cur = bufA;
        float* nxt = bufB;
        for (int l = 0; l < 3; ++l) {
            hipMemsetAsync(nxt, 0, NB, stream);
            spmm_atomic_kernel<<<2048, 256, 0, stream>>>(adj_val, adj_row,
                                                         adj_col, cur, nxt);
            accum_scale_kernel<<<2048, 256, 0, stream>>>(acc, nxt, 0.25f);
            float* t = cur; cur = nxt; nxt = t;
        }
    }

    gather_kernel<<<768, 256, 0, stream>>>(final_emb, users, pos_items,
                                           neg_items, out_sel);
}